// Round 9
// baseline (174.884 us; speedup 1.0000x reference)
//
#include <hip/hip_runtime.h>
#include <math.h>

// PhaseShift: out = unwrap(atan2(xi,xr) - atan2(xi[ch0],xr[ch0]), axis=F)
// Shapes: [N=16, CH=4, F=513, T=512] fp32.
//
// Occupancy round v2. R6 (53.5us) is latency-bound at 16 waves/CU; R7
// (narrow t) and R8 (float2 ILP) both proved the other levers are dead
// (coalescing disaster / VGPR-64 spill wall). So: split the F-chain in
// half across blocks -> grid 512 x 1024 = 2 blocks/CU = 32 waves/CU, and
// resolve the cross-half prefix with a tiny second kernel (stream-ordered;
// no cooperative launch, graph-capture safe).
//   Kernel A: block = (n, t-tile of 32, half). half0 = f 0..256 (257 rows,
//   seg31 takes 9), half1 = f 257..512 (256 rows). Inside = exact R6
//   streaming skeleton (32 segs x 8 rows, LDS scan, local pass-2 RMW; NO
//   per-thread arrays -- R1/R2/R4/R8 all spilled). Half-0 seg-31 threads
//   write per-column total corrections (3ch x 32t) to d_ws.
//   Kernel B: out[f>=257, ch1-3] += ws total (L3-hot RMW, nt store).
// dd bit-sequence unchanged (channel-fused a0, bounded exact mod, boundary
// pprev same expression) -- no pi-boundary lottery re-roll; only summation
// association moves (ULP noise vs 3.58 threshold).

#define NN    16
#define CHN   4
#define FF    513
#define TT    512
#define PLANE (FF * TT)      // 262656
#define NSEG  32
#define SEGB  8
#define H1F   257            // first row of half 1

__device__ __forceinline__ float phase_corr(float dd) {
    // np.unwrap step: ddmod = pymod(dd+pi, 2pi) - pi; edge rule; gate |dd|<pi.
    // dd in (-4pi, 4pi) -> x = dd+pi in (-3pi, 5pi): <=2 exact +-2pi steps.
    const float PIF  = 3.14159265358979323846f;   // 0x40490FDB
    const float TPIF = 6.28318530717958647692f;   // 0x40C90FDB = 2*PIF exactly
    float x = dd + PIF;
    x = (x >= TPIF) ? x - TPIF : x;
    x = (x >= TPIF) ? x - TPIF : x;
    x = (x < 0.0f)  ? x + TPIF : x;
    x = (x < 0.0f)  ? x + TPIF : x;
    float ddmod = x - PIF;
    if (ddmod == -PIF && dd > 0.0f) ddmod = PIF;
    return (fabsf(dd) < PIF) ? 0.0f : (ddmod - dd);
}

__global__ __launch_bounds__(1024) void phase_unwrap_A(
    const float* __restrict__ xr, const float* __restrict__ xi,
    float* __restrict__ out, float* __restrict__ ws)
{
    const int tid  = threadIdx.x;
    const int tl   = tid & 31;      // t within tile
    const int seg  = tid >> 5;      // 0..31 F-segment
    const int bid  = blockIdx.x;
    const int half = bid & 1;
    const int tt   = (bid >> 1) & 15;
    const int n    = bid >> 5;
    const int t    = tt * 32 + tl;

    const unsigned base = (unsigned)(n * CHN * PLANE) + (unsigned)t;
    const int fbase = half ? H1F : 0;
    const int f0    = fbase + seg * SEGB;
    const int cnt   = (!half && seg == NSEG - 1) ? 9 : 8;   // half0 seg31: +row 256

    __shared__ float segsum[3][NSEG][32];

    // Boundary phases at f0-1 (all segs except half0 seg0).
    float pprev0 = 0.0f, pprev1 = 0.0f, pprev2 = 0.0f;
    if (f0 > 0) {
        const unsigned off = base + (unsigned)(f0 - 1) * TT;
        const float a0 = atan2f(xi[off], xr[off]);
        pprev0 = atan2f(xi[off + 1u * PLANE], xr[off + 1u * PLANE]) - a0;
        pprev1 = atan2f(xi[off + 2u * PLANE], xr[off + 2u * PLANE]) - a0;
        pprev2 = atan2f(xi[off + 3u * PLANE], xr[off + 3u * PLANE]) - a0;
    }

    // Pass 1: shared a0, three correction chains, stream stores.
    float acc0 = 0.0f, acc1 = 0.0f, acc2 = 0.0f;
    unsigned off = base + (unsigned)f0 * TT;
    #pragma unroll 8
    for (int k = 0; k < cnt; ++k, off += TT) {
        const float a0  = atan2f(xi[off], xr[off]);
        const float pc0 = atan2f(xi[off + 1u * PLANE], xr[off + 1u * PLANE]) - a0;
        const float pc1 = atan2f(xi[off + 2u * PLANE], xr[off + 2u * PLANE]) - a0;
        const float pc2 = atan2f(xi[off + 3u * PLANE], xr[off + 3u * PLANE]) - a0;
        if (f0 > 0 || k > 0) {             // skip only global row 0
            acc0 += phase_corr(pc0 - pprev0);
            acc1 += phase_corr(pc1 - pprev1);
            acc2 += phase_corr(pc2 - pprev2);
        }
        __builtin_nontemporal_store(0.0f, &out[off]);   // ch0: final, never re-read
        out[off + 1u * PLANE] = pc0 + acc0;             // cached: RMW re-reads
        out[off + 2u * PLANE] = pc1 + acc1;
        out[off + 3u * PLANE] = pc2 + acc2;
        pprev0 = pc0; pprev1 = pc1; pprev2 = pc2;
    }

    segsum[0][seg][tl] = acc0;
    segsum[1][seg][tl] = acc1;
    segsum[2][seg][tl] = acc2;
    __syncthreads();

    // Exclusive prefix over segments (broadcast LDS reads).
    float run0 = 0.0f, run1 = 0.0f, run2 = 0.0f;
    for (int v = 0; v < NSEG - 1; ++v) {
        if (v < seg) {
            run0 += segsum[0][v][tl];
            run1 += segsum[1][v][tl];
            run2 += segsum[2][v][tl];
        }
    }

    // Half-0 total correction per column -> ws (seg 31 holds run+acc = total).
    if (!half && seg == NSEG - 1) {
        const unsigned w = (unsigned)((n * 16 + tt) * 3) * 32u + (unsigned)tl;
        ws[w]           = run0 + acc0;
        ws[w + 32u]     = run1 + acc1;
        ws[w + 64u]     = run2 + acc2;
    }

    if (seg > 0) {
        // Pass 2: RMW our own freshly-written rows (L2-hot).
        unsigned o2 = base + (unsigned)f0 * TT;
        #pragma unroll 8
        for (int k = 0; k < cnt; ++k, o2 += TT) {
            out[o2 + 1u * PLANE] += run0;
            out[o2 + 2u * PLANE] += run1;
            out[o2 + 3u * PLANE] += run2;
        }
    }
}

__global__ __launch_bounds__(1024) void phase_unwrap_B(
    float* __restrict__ out, const float* __restrict__ ws)
{
    const int tid = threadIdx.x;
    const int tl  = tid & 31;       // t within tile
    const int rg  = tid >> 5;       // 0..31 row-group (8 rows each)
    const int bid = blockIdx.x;
    const int tt  = bid & 15;
    const int n   = bid >> 4;
    const int t   = tt * 32 + tl;

    const unsigned w = (unsigned)((n * 16 + tt) * 3) * 32u + (unsigned)tl;
    const float run0 = ws[w];
    const float run1 = ws[w + 32u];
    const float run2 = ws[w + 64u];

    const unsigned base = (unsigned)(n * CHN * PLANE) + (unsigned)t;
    unsigned off = base + (unsigned)(H1F + rg * SEGB) * TT;
    #pragma unroll 8
    for (int k = 0; k < 8; ++k, off += TT) {
        const float v0 = out[off + 1u * PLANE] + run0;
        const float v1 = out[off + 2u * PLANE] + run1;
        const float v2 = out[off + 3u * PLANE] + run2;
        __builtin_nontemporal_store(v0, &out[off + 1u * PLANE]);
        __builtin_nontemporal_store(v1, &out[off + 2u * PLANE]);
        __builtin_nontemporal_store(v2, &out[off + 3u * PLANE]);
    }
}

extern "C" void kernel_launch(void* const* d_in, const int* in_sizes, int n_in,
                              void* d_out, int out_size, void* d_ws, size_t ws_size,
                              hipStream_t stream) {
    const float* xr = (const float*)d_in[0];
    const float* xi = (const float*)d_in[1];
    float* out = (float*)d_out;
    float* ws  = (float*)d_ws;      // 16*16*3*32 floats = 96 KB

    dim3 gA(NN * (TT / 32) * 2);    // 512 blocks = 2 blocks/CU = 32 waves/CU
    dim3 bA(1024);                  // 32 segments x 32 t-lanes
    phase_unwrap_A<<<gA, bA, 0, stream>>>(xr, xi, out, ws);

    dim3 gB(NN * (TT / 32));        // 256 blocks
    dim3 bB(1024);                  // 32 row-groups x 32 t-lanes
    phase_unwrap_B<<<gB, bB, 0, stream>>>(out, ws);
}

// Round 10
// 63.905 us; speedup vs baseline: 2.7366x; 2.7366x over previous
//
#include <hip/hip_runtime.h>
#include <math.h>

// PhaseShift: out = unwrap(atan2(xi,xr) - atan2(xi[ch0],xr[ch0]), axis=F)
// Shapes: [N=16, CH=4, F=513, T=512] fp32.
//
// Occupancy round v3. R9's F-split spilled ONLY because cnt was a runtime
// 8-or-9 under #pragma unroll (compiler peeled + hoisted past the 64-VGPR
// wall it enforces for 1024-thread blocks; R7/R8 same signature). Fix:
// compile-time trip count 8 EVERYWHERE.
//   Kernel A (512 blocks = 2/CU = 32 waves/CU): half h = rows [h*256,
//   h*256+256), 32 segs x 8 rows exactly. R6 streaming body (NO per-thread
//   arrays): pass 1 streams pc+acc (ch0 = nt zeros), LDS scan, local pass-2
//   RMW. Seg-31 threads write each half's total correction to ws.
//   Kernel B (256 blocks): rows 256..511 ch1-3 += ws0 (L3-hot RMW, nt);
//   rg31 also computes the peeled row 512: pc511/pc512 recomputed with the
//   SAME fused-a0 expressions (bit-identical), out512 = pc512 + ws0 + ws1
//   + corr(511->512); ch0 row 512 = 0.
// dd bit-sequence unchanged -> no pi-boundary lottery re-roll; only sum
// association moves (ULP noise vs 3.58 threshold).

#define NN    16
#define CHN   4
#define FF    513
#define TT    512
#define PLANE (FF * TT)      // 262656
#define NSEG  32
#define SEGB  8
#define HROWS 256            // rows per half
#define WSH   (16 * 16 * 3 * 32)   // floats per half-total table

__device__ __forceinline__ float phase_corr(float dd) {
    // np.unwrap step: ddmod = pymod(dd+pi, 2pi) - pi; edge rule; gate |dd|<pi.
    // dd in (-4pi, 4pi) -> x = dd+pi in (-3pi, 5pi): <=2 exact +-2pi steps.
    const float PIF  = 3.14159265358979323846f;   // 0x40490FDB
    const float TPIF = 6.28318530717958647692f;   // 0x40C90FDB = 2*PIF exactly
    float x = dd + PIF;
    x = (x >= TPIF) ? x - TPIF : x;
    x = (x >= TPIF) ? x - TPIF : x;
    x = (x < 0.0f)  ? x + TPIF : x;
    x = (x < 0.0f)  ? x + TPIF : x;
    float ddmod = x - PIF;
    if (ddmod == -PIF && dd > 0.0f) ddmod = PIF;
    return (fabsf(dd) < PIF) ? 0.0f : (ddmod - dd);
}

__global__ __launch_bounds__(1024) void phase_unwrap_A(
    const float* __restrict__ xr, const float* __restrict__ xi,
    float* __restrict__ out, float* __restrict__ ws)
{
    const int tid  = threadIdx.x;
    const int tl   = tid & 31;      // t within tile
    const int seg  = tid >> 5;      // 0..31 F-segment
    const int bid  = blockIdx.x;
    const int half = bid & 1;
    const int tt   = (bid >> 1) & 15;
    const int n    = bid >> 5;
    const int t    = tt * 32 + tl;

    const unsigned base = (unsigned)(n * CHN * PLANE) + (unsigned)t;
    const int f0 = half * HROWS + seg * SEGB;

    __shared__ float segsum[3][NSEG][32];

    // Boundary phases at f0-1 (all segs except global row 0).
    float pprev0 = 0.0f, pprev1 = 0.0f, pprev2 = 0.0f;
    if (f0 > 0) {
        const unsigned off = base + (unsigned)(f0 - 1) * TT;
        const float a0 = atan2f(xi[off], xr[off]);
        pprev0 = atan2f(xi[off + 1u * PLANE], xr[off + 1u * PLANE]) - a0;
        pprev1 = atan2f(xi[off + 2u * PLANE], xr[off + 2u * PLANE]) - a0;
        pprev2 = atan2f(xi[off + 3u * PLANE], xr[off + 3u * PLANE]) - a0;
    }

    // Pass 1: shared a0, three correction chains, stream stores.
    // Compile-time trip count (R7/R8/R9 spill lesson: no runtime 8-or-9).
    float acc0 = 0.0f, acc1 = 0.0f, acc2 = 0.0f;
    unsigned off = base + (unsigned)f0 * TT;
    #pragma unroll 4
    for (int k = 0; k < SEGB; ++k, off += TT) {
        const float a0  = atan2f(xi[off], xr[off]);
        const float pc0 = atan2f(xi[off + 1u * PLANE], xr[off + 1u * PLANE]) - a0;
        const float pc1 = atan2f(xi[off + 2u * PLANE], xr[off + 2u * PLANE]) - a0;
        const float pc2 = atan2f(xi[off + 3u * PLANE], xr[off + 3u * PLANE]) - a0;
        if (f0 > 0 || k > 0) {             // skip only global row 0
            acc0 += phase_corr(pc0 - pprev0);
            acc1 += phase_corr(pc1 - pprev1);
            acc2 += phase_corr(pc2 - pprev2);
        }
        __builtin_nontemporal_store(0.0f, &out[off]);   // ch0: final, never re-read
        out[off + 1u * PLANE] = pc0 + acc0;             // cached: RMW re-reads
        out[off + 2u * PLANE] = pc1 + acc1;
        out[off + 3u * PLANE] = pc2 + acc2;
        pprev0 = pc0; pprev1 = pc1; pprev2 = pc2;
    }

    segsum[0][seg][tl] = acc0;
    segsum[1][seg][tl] = acc1;
    segsum[2][seg][tl] = acc2;
    __syncthreads();

    // Exclusive prefix over segments (broadcast LDS reads).
    float run0 = 0.0f, run1 = 0.0f, run2 = 0.0f;
    for (int v = 0; v < NSEG - 1; ++v) {
        if (v < seg) {
            run0 += segsum[0][v][tl];
            run1 += segsum[1][v][tl];
            run2 += segsum[2][v][tl];
        }
    }

    // Each half's total correction per column -> ws (seg 31: run+acc = total).
    if (seg == NSEG - 1) {
        const unsigned w = (unsigned)half * WSH
                         + (unsigned)((n * 16 + tt) * 3) * 32u + (unsigned)tl;
        ws[w]        = run0 + acc0;
        ws[w + 32u]  = run1 + acc1;
        ws[w + 64u]  = run2 + acc2;
    }

    if (seg > 0) {
        // Pass 2: RMW our own freshly-written rows (L2-hot).
        unsigned o2 = base + (unsigned)f0 * TT;
        #pragma unroll 4
        for (int k = 0; k < SEGB; ++k, o2 += TT) {
            out[o2 + 1u * PLANE] += run0;
            out[o2 + 2u * PLANE] += run1;
            out[o2 + 3u * PLANE] += run2;
        }
    }
}

__global__ __launch_bounds__(1024) void phase_unwrap_B(
    const float* __restrict__ xr, const float* __restrict__ xi,
    float* __restrict__ out, const float* __restrict__ ws)
{
    const int tid = threadIdx.x;
    const int tl  = tid & 31;       // t within tile
    const int rg  = tid >> 5;       // 0..31 row-group (8 rows each)
    const int bid = blockIdx.x;
    const int tt  = bid & 15;
    const int n   = bid >> 4;
    const int t   = tt * 32 + tl;

    const unsigned w = (unsigned)((n * 16 + tt) * 3) * 32u + (unsigned)tl;
    const float h00 = ws[w], h01 = ws[w + 32u], h02 = ws[w + 64u];

    const unsigned base = (unsigned)(n * CHN * PLANE) + (unsigned)t;

    // RMW rows 256..511, ch1-3: += half-0 total.
    unsigned off = base + (unsigned)(HROWS + rg * SEGB) * TT;
    #pragma unroll 4
    for (int k = 0; k < SEGB; ++k, off += TT) {
        const float v0 = out[off + 1u * PLANE] + h00;
        const float v1 = out[off + 2u * PLANE] + h01;
        const float v2 = out[off + 3u * PLANE] + h02;
        __builtin_nontemporal_store(v0, &out[off + 1u * PLANE]);
        __builtin_nontemporal_store(v1, &out[off + 2u * PLANE]);
        __builtin_nontemporal_store(v2, &out[off + 3u * PLANE]);
    }

    // Peeled row 512 (rg 31): pc511/pc512 recomputed bit-identically.
    if (rg == 31) {
        const float h10 = ws[w + WSH], h11 = ws[w + WSH + 32u], h12 = ws[w + WSH + 64u];
        const unsigned o511 = base + 511u * TT;
        const unsigned o512 = base + 512u * TT;
        const float a0p = atan2f(xi[o511], xr[o511]);
        const float q0p = atan2f(xi[o511 + 1u * PLANE], xr[o511 + 1u * PLANE]) - a0p;
        const float q1p = atan2f(xi[o511 + 2u * PLANE], xr[o511 + 2u * PLANE]) - a0p;
        const float q2p = atan2f(xi[o511 + 3u * PLANE], xr[o511 + 3u * PLANE]) - a0p;
        const float a0c = atan2f(xi[o512], xr[o512]);
        const float q0c = atan2f(xi[o512 + 1u * PLANE], xr[o512 + 1u * PLANE]) - a0c;
        const float q1c = atan2f(xi[o512 + 2u * PLANE], xr[o512 + 2u * PLANE]) - a0c;
        const float q2c = atan2f(xi[o512 + 3u * PLANE], xr[o512 + 3u * PLANE]) - a0c;
        __builtin_nontemporal_store(0.0f, &out[o512]);
        __builtin_nontemporal_store(q0c + h00 + h10 + phase_corr(q0c - q0p), &out[o512 + 1u * PLANE]);
        __builtin_nontemporal_store(q1c + h01 + h11 + phase_corr(q1c - q1p), &out[o512 + 2u * PLANE]);
        __builtin_nontemporal_store(q2c + h02 + h12 + phase_corr(q2c - q2p), &out[o512 + 3u * PLANE]);
    }
}

extern "C" void kernel_launch(void* const* d_in, const int* in_sizes, int n_in,
                              void* d_out, int out_size, void* d_ws, size_t ws_size,
                              hipStream_t stream) {
    const float* xr = (const float*)d_in[0];
    const float* xi = (const float*)d_in[1];
    float* out = (float*)d_out;
    float* ws  = (float*)d_ws;      // 2 * 24576 floats = 192 KB

    dim3 gA(NN * 16 * 2);           // 512 blocks = 2 blocks/CU = 32 waves/CU
    dim3 bA(1024);                  // 32 segments x 32 t-lanes
    phase_unwrap_A<<<gA, bA, 0, stream>>>(xr, xi, out, ws);

    dim3 gB(NN * 16);               // 256 blocks
    dim3 bB(1024);                  // 32 row-groups x 32 t-lanes
    phase_unwrap_B<<<gB, bB, 0, stream>>>(xr, xi, out, ws);
}

// Round 11
// 57.771 us; speedup vs baseline: 3.0272x; 1.1062x over previous
//
#include <hip/hip_runtime.h>
#include <math.h>

// PhaseShift: out = unwrap(atan2(xi,xr) - atan2(xi[ch0],xr[ch0]), axis=F)
// Shapes: [N=16, CH=4, F=513, T=512] fp32.
//
// R6 skeleton, float4-wide. R10 proved occupancy is NOT the wall (34->59%
// at identical wall time); effective BW is 3.9 of 6.3 TB/s with all-dword
// accesses and one serial chain per lane. So: each lane owns 4 adjacent t
// (float4, 16B/lane = the measured-ceiling access width), block = 512 thr
// = 8 float4-lanes (32 t, full 128B lines -- R7 lesson) x 64 segs of 8 rows.
// __launch_bounds__(512,2): VGPR cap 128 (the 1024-thr blocks were pinned
// to 64 and spilled every array attempt). NO per-thread arrays. Streaming
// pass 1 (ch0 = nt zeros), LDS scan of per-seg correction sums, pass 2 RMW
// (L2-hot, nt final). Row 512 peeled into seg 63 (pprev = pc511 already).
// dd bit-sequence unchanged (channel-fused a0, bounded exact mod, same
// per-column order) -- no pi-boundary lottery re-roll; only sum association
// moves (ULP noise, proven safe R5->R6->R10).

#define NN    16
#define CHN   4
#define FF    513
#define TT    512
#define PLANE (FF * TT)      // 262656
#define P4    (PLANE / 4)    // 65664 float4 per plane
#define T4    (TT / 4)       // 128 float4 per row
#define NSEG  64
#define SEGB  8

typedef float v4 __attribute__((ext_vector_type(4)));

__device__ __forceinline__ float phase_corr(float dd) {
    // np.unwrap step: ddmod = pymod(dd+pi, 2pi) - pi; edge rule; gate |dd|<pi.
    // dd in (-4pi, 4pi) -> x = dd+pi in (-3pi, 5pi): <=2 exact +-2pi steps.
    const float PIF  = 3.14159265358979323846f;   // 0x40490FDB
    const float TPIF = 6.28318530717958647692f;   // 0x40C90FDB = 2*PIF exactly
    float x = dd + PIF;
    x = (x >= TPIF) ? x - TPIF : x;
    x = (x >= TPIF) ? x - TPIF : x;
    x = (x < 0.0f)  ? x + TPIF : x;
    x = (x < 0.0f)  ? x + TPIF : x;
    float ddmod = x - PIF;
    if (ddmod == -PIF && dd > 0.0f) ddmod = PIF;
    return (fabsf(dd) < PIF) ? 0.0f : (ddmod - dd);
}

__global__ __launch_bounds__(512, 2) void phase_unwrap_kernel(
    const float* __restrict__ xr, const float* __restrict__ xi,
    float* __restrict__ out)
{
    const int tid  = threadIdx.x;
    const int lane = tid & 7;       // 8 float4 lanes = 32 t
    const int seg  = tid >> 3;      // 0..63 F-segment
    const int bid  = blockIdx.x;
    const int tt   = bid & 15;      // 16 tiles of 32 t
    const int n    = bid >> 4;

    const v4* __restrict__ xr4  = (const v4*)xr;
    const v4* __restrict__ xi4  = (const v4*)xi;
    v4* __restrict__       out4 = (v4*)out;

    const unsigned base = (unsigned)(n * CHN) * (unsigned)P4
                        + (unsigned)(tt * 8 + lane);
    const int f0 = seg * SEGB;

    __shared__ v4 segsum[3][NSEG][8];   // 24 KB

    // Boundary phases at f0-1 (segs 1..63).
    v4 pp0 = {0.f,0.f,0.f,0.f}, pp1 = {0.f,0.f,0.f,0.f}, pp2 = {0.f,0.f,0.f,0.f};
    if (seg > 0) {
        const unsigned o = base + (unsigned)(f0 - 1) * T4;
        const v4 r0 = xr4[o],           i0 = xi4[o];
        const v4 r1 = xr4[o + P4],      i1 = xi4[o + P4];
        const v4 r2 = xr4[o + 2u * P4], i2 = xi4[o + 2u * P4];
        const v4 r3 = xr4[o + 3u * P4], i3 = xi4[o + 3u * P4];
        #pragma unroll
        for (int j = 0; j < 4; ++j) {
            const float a0 = atan2f(i0[j], r0[j]);
            pp0[j] = atan2f(i1[j], r1[j]) - a0;
            pp1[j] = atan2f(i2[j], r2[j]) - a0;
            pp2[j] = atan2f(i3[j], r3[j]) - a0;
        }
    }

    // Pass 1: shared a0, 12 independent correction chains, stream stores.
    v4 acc0 = {0.f,0.f,0.f,0.f}, acc1 = {0.f,0.f,0.f,0.f}, acc2 = {0.f,0.f,0.f,0.f};
    unsigned off = base + (unsigned)f0 * T4;
    #pragma unroll 2
    for (int k = 0; k < SEGB; ++k, off += T4) {
        const v4 r0 = xr4[off],           i0 = xi4[off];
        const v4 r1 = xr4[off + P4],      i1 = xi4[off + P4];
        const v4 r2 = xr4[off + 2u * P4], i2 = xi4[off + 2u * P4];
        const v4 r3 = xr4[off + 3u * P4], i3 = xi4[off + 3u * P4];
        v4 pc0, pc1, pc2;
        #pragma unroll
        for (int j = 0; j < 4; ++j) {
            const float a0 = atan2f(i0[j], r0[j]);
            pc0[j] = atan2f(i1[j], r1[j]) - a0;
            pc1[j] = atan2f(i2[j], r2[j]) - a0;
            pc2[j] = atan2f(i3[j], r3[j]) - a0;
        }
        if (seg > 0 || k > 0) {            // skip only global row 0
            #pragma unroll
            for (int j = 0; j < 4; ++j) {
                acc0[j] += phase_corr(pc0[j] - pp0[j]);
                acc1[j] += phase_corr(pc1[j] - pp1[j]);
                acc2[j] += phase_corr(pc2[j] - pp2[j]);
            }
        }
        const v4 z = {0.f,0.f,0.f,0.f};
        __builtin_nontemporal_store(z, &out4[off]);     // ch0: final, never re-read
        out4[off + P4]      = pc0 + acc0;               // cached: RMW re-reads
        out4[off + 2u * P4] = pc1 + acc1;
        out4[off + 3u * P4] = pc2 + acc2;
        pp0 = pc0; pp1 = pc1; pp2 = pc2;
    }

    segsum[0][seg][lane] = acc0;
    segsum[1][seg][lane] = acc1;
    segsum[2][seg][lane] = acc2;
    __syncthreads();

    // Exclusive prefix over segments (broadcast LDS reads).
    v4 run0 = {0.f,0.f,0.f,0.f}, run1 = {0.f,0.f,0.f,0.f}, run2 = {0.f,0.f,0.f,0.f};
    for (int v = 0; v < NSEG - 1; ++v) {
        if (v < seg) {
            run0 += segsum[0][v][lane];
            run1 += segsum[1][v][lane];
            run2 += segsum[2][v][lane];
        }
    }

    if (seg > 0) {
        // Pass 2: RMW our own freshly-written rows (L2-hot), nt final store.
        unsigned o2 = base + (unsigned)f0 * T4;
        #pragma unroll 2
        for (int k = 0; k < SEGB; ++k, o2 += T4) {
            const v4 a = out4[o2 + P4]      + run0;
            const v4 b = out4[o2 + 2u * P4] + run1;
            const v4 c = out4[o2 + 3u * P4] + run2;
            __builtin_nontemporal_store(a, &out4[o2 + P4]);
            __builtin_nontemporal_store(b, &out4[o2 + 2u * P4]);
            __builtin_nontemporal_store(c, &out4[o2 + 3u * P4]);
        }
    }

    // Peeled row 512 (seg 63; pp* = pc at row 511, bit-identical chain).
    if (seg == NSEG - 1) {
        const unsigned o = base + 512u * T4;
        const v4 r0 = xr4[o],           i0 = xi4[o];
        const v4 r1 = xr4[o + P4],      i1 = xi4[o + P4];
        const v4 r2 = xr4[o + 2u * P4], i2 = xi4[o + 2u * P4];
        const v4 r3 = xr4[o + 3u * P4], i3 = xi4[o + 3u * P4];
        v4 c0, c1, c2;
        #pragma unroll
        for (int j = 0; j < 4; ++j) {
            const float a0 = atan2f(i0[j], r0[j]);
            const float q0 = atan2f(i1[j], r1[j]) - a0;
            const float q1 = atan2f(i2[j], r2[j]) - a0;
            const float q2 = atan2f(i3[j], r3[j]) - a0;
            c0[j] = q0 + run0[j] + acc0[j] + phase_corr(q0 - pp0[j]);
            c1[j] = q1 + run1[j] + acc1[j] + phase_corr(q1 - pp1[j]);
            c2[j] = q2 + run2[j] + acc2[j] + phase_corr(q2 - pp2[j]);
        }
        const v4 z = {0.f,0.f,0.f,0.f};
        __builtin_nontemporal_store(z,  &out4[o]);
        __builtin_nontemporal_store(c0, &out4[o + P4]);
        __builtin_nontemporal_store(c1, &out4[o + 2u * P4]);
        __builtin_nontemporal_store(c2, &out4[o + 3u * P4]);
    }
}

extern "C" void kernel_launch(void* const* d_in, const int* in_sizes, int n_in,
                              void* d_out, int out_size, void* d_ws, size_t ws_size,
                              hipStream_t stream) {
    const float* xr = (const float*)d_in[0];
    const float* xi = (const float*)d_in[1];
    float* out = (float*)d_out;

    dim3 grid(NN * 16);    // 256 blocks = 1 block/CU
    dim3 block(512);       // 64 segments x 8 float4-lanes (32 t)
    phase_unwrap_kernel<<<grid, block, 0, stream>>>(xr, xi, out);
}